// Round 11
// baseline (349.311 us; speedup 1.0000x reference)
//
#include <hip/hip_runtime.h>
#include <hip/hip_bf16.h>
#include <math.h>

// B=8, H=W=128, C=hidden=256, N=16384, Mtot=131072.
#define Hc   128
#define Wc   128
#define Cc   256
#define Nc   (Hc * Wc)
#define Bn   8
#define Mtot (Bn * Nc)          // 131072
#define CSZ  52                 // ceil(256/5)
#define SPAD 2

typedef unsigned short ushort4v __attribute__((ext_vector_type(4)));
typedef unsigned short ushort8  __attribute__((ext_vector_type(8)));
typedef __bf16         bf16x8   __attribute__((ext_vector_type(8)));
typedef float          f32x4    __attribute__((ext_vector_type(4)));

__device__ __forceinline__ float bf2f(unsigned short u) {
    return __uint_as_float(((unsigned)u) << 16);
}
__device__ __forceinline__ unsigned short f2bf(float f) {   // RNE
    unsigned u = __float_as_uint(f);
    return (unsigned short)((u + 0x7fffu + ((u >> 16) & 1u)) >> 16);
}
// pack two floats -> two bf16 (a -> low16). Round-half-up (ok vs bf16 eps).
__device__ __forceinline__ unsigned pk2bf(float a, float b) {
    unsigned ua = __float_as_uint(a) + 0x8000u;
    unsigned ub = __float_as_uint(b) + 0x8000u;
    return __builtin_amdgcn_perm(ub, ua, 0x07060302);
}
__device__ __forceinline__ void async16(const void* g, void* l) {
    __builtin_amdgcn_global_load_lds(
        (const __attribute__((address_space(1))) unsigned*)g,
        (__attribute__((address_space(3))) unsigned*)l, 16, 0, 0);
}

// Counted-vmcnt fence + raw barrier (T4). lgkmcnt(0) REQUIRED (r9 failed
// without it: pending ds_reads crossed the barrier and raced the next
// tile's global_load_lds DMA into a recycled buffer).
#define FENCE(vm) asm volatile("s_waitcnt vmcnt(" #vm ") lgkmcnt(0)\n\ts_barrier" ::: "memory")

// ---------------------------------------------------------------------------
// P0+P1 merged: H-shift + fp32->bf16 convert of x (all 4096 blocks), plus
// weight prep (blocks 0..63): w1,w2 fp32->bf16; dw_w [ch][tap]->dwT [tap][ch].
// ---------------------------------------------------------------------------
__global__ __launch_bounds__(256)
void shiftwprep_kernel(const float* __restrict__ x, unsigned short* __restrict__ xb,
                       const float* __restrict__ w1, const float* __restrict__ w2,
                       const float* __restrict__ dw_w,
                       unsigned short* __restrict__ w1b, unsigned short* __restrict__ w2b,
                       float* __restrict__ dwT)
{
    const int gid0 = blockIdx.x * 256 + threadIdx.x;
    if (blockIdx.x < 64) {                            // weight prep (16384 thr)
        const int g = gid0;
        {
            float4 a = *(const float4*)(w1 + (size_t)g * 4);
            ushort4v o = { f2bf(a.x), f2bf(a.y), f2bf(a.z), f2bf(a.w) };
            *(ushort4v*)(w1b + (size_t)g * 4) = o;
        }
        {
            float4 a = *(const float4*)(w2 + (size_t)g * 4);
            ushort4v o = { f2bf(a.x), f2bf(a.y), f2bf(a.z), f2bf(a.w) };
            *(ushort4v*)(w2b + (size_t)g * 4) = o;
        }
        if (g < 9 * Cc) dwT[(g % 9) * Cc + g / 9] = dw_w[g];
    }
#pragma unroll
    for (int it = 0; it < 4; ++it) {
        const int gid = gid0 + it * (4096 * 256);   // 4.19M chunks total
        const int row = gid >> 5;                   // b*16384 + h*128 + w
        const int c   = (gid & 31) * 8;
        const int hh  = (row >> 7) & 127;
        const int s0  = c / CSZ - SPAD;
        const int s1  = (c + 4) / CSZ - SPAD;
        const int h0  = hh - s0, h1r = hh - s1;
        float4 v0 = make_float4(0.f, 0.f, 0.f, 0.f);
        float4 v1 = make_float4(0.f, 0.f, 0.f, 0.f);
        if (h0  >= 0 && h0  < Hc)
            v0 = *(const float4*)(x + ((size_t)row + (size_t)(h0 - hh) * Wc) * Cc + c);
        if (h1r >= 0 && h1r < Hc)
            v1 = *(const float4*)(x + ((size_t)row + (size_t)(h1r - hh) * Wc) * Cc + c + 4);
        uint4 o;
        o.x = pk2bf(v0.x, v0.y); o.y = pk2bf(v0.z, v0.w);
        o.z = pk2bf(v1.x, v1.y); o.w = pk2bf(v1.z, v1.w);
        *(uint4*)(xb + (size_t)row * Cc + c) = o;
    }
}

// ---------------------------------------------------------------------------
// K1: h1 = x_shifted_bf16 @ w1^T + b1. 128(M) x 256(N=full) tile, BK=32,
// 3-buffer 2-step-lookahead counted-vmcnt pipeline. Per fence: 32 MFMAs +
// 12 ds_reads per wave (2x r10) -> lookahead work ~600cyc >= load latency.
// Source-XOR chunk swizzle (m173: LDS linear for global_load_lds, global
// source chunk ^= row&3; read XOR folds to lane constant axo) -> ds_read
// conflicts 4-way -> 2-way(free). LDS 73728 (3 x 24KB; Cs unions) -> 2
// blocks/CU. Grid 1024 (A-panel staged once, prologue/epilogue amortized 2x).
// ---------------------------------------------------------------------------
__global__ __launch_bounds__(256)
void fc1_mfma_kernel(const unsigned short* __restrict__ xb, const unsigned short* __restrict__ w1b,
                     const float* __restrict__ b1, unsigned short* __restrict__ h1)
{
    __shared__ __align__(16) unsigned char sm[73728];
    unsigned short* Cs = (unsigned short*)sm;       // [128][136] epilogue union

    const int tid  = threadIdx.x;
    const int lane = tid & 63;
    const int wave = tid >> 6;
    const int wm = (wave >> 1) * 64;
    const int wn = (wave & 1) * 128;

    // grid 1024 = 8*128: bijective XCD swizzle.
    const int lid = ((blockIdx.x & 7) << 7) | (blockIdx.x >> 3);
    const size_t m0 = (size_t)lid * 128;

    // A: 512 chunks (2/thread), B: 1024 chunks (4/thread); 16B chunks.
    const int qa0 = tid, qa1 = tid + 256;
    const int ra0 = qa0 >> 2, ra1 = qa1 >> 2;
    const size_t aof0 = (m0 + ra0) * Cc + (((qa0 & 3) ^ (ra0 & 3)) << 3);
    const size_t aof1 = (m0 + ra1) * Cc + (((qa1 & 3) ^ (ra1 & 3)) << 3);
    const int qb0 = tid, qb1 = tid + 256, qb2 = tid + 512, qb3 = tid + 768;
    const int rb0 = qb0 >> 2, rb1 = qb1 >> 2, rb2 = qb2 >> 2, rb3 = qb3 >> 2;
    const int bof0 = rb0 * Cc + (((qb0 & 3) ^ (rb0 & 3)) << 3);
    const int bof1 = rb1 * Cc + (((qb1 & 3) ^ (rb1 & 3)) << 3);
    const int bof2 = rb2 * Cc + (((qb2 & 3) ^ (rb2 & 3)) << 3);
    const int bof3 = rb3 * Cc + (((qb3 & 3) ^ (rb3 & 3)) << 3);

    auto stage = [&](int buf, int t) {         // 6 async16/thread = 6 vmcnt
        const int k0 = t * 32;
        unsigned char* ad = sm + buf * 24576;
        unsigned char* bd = ad + 8192;
        async16(xb  + aof0 + k0, ad + qa0 * 16);
        async16(xb  + aof1 + k0, ad + qa1 * 16);
        async16(w1b + bof0 + k0, bd + qb0 * 16);
        async16(w1b + bof1 + k0, bd + qb1 * 16);
        async16(w1b + bof2 + k0, bd + qb2 * 16);
        async16(w1b + bof3 + k0, bd + qb3 * 16);
    };

    f32x4 acc[4][8] = {};
    const int rr  = lane & 15;
    const int axo = (((lane >> 4) ^ (rr & 3)) << 3);   // read-side XOR (lane const)

    stage(0, 0);
    stage(1, 1);
    FENCE(6);

#define G1_STEP(T, FN)                                                        \
    {                                                                          \
        if constexpr ((T) <= 5) stage(((T) + 2) % 3, (T) + 2);                 \
        const __bf16* ap = (const __bf16*)(sm + ((T) % 3) * 24576);            \
        const __bf16* bp = (const __bf16*)(sm + ((T) % 3) * 24576 + 8192);     \
        bf16x8 a[4];                                                           \
        _Pragma("unroll")                                                      \
        for (int i = 0; i < 4; ++i)                                            \
            a[i] = *(const bf16x8*)(ap + (wm + i * 16 + rr) * 32 + axo);       \
        _Pragma("unroll")                                                      \
        for (int jh = 0; jh < 2; ++jh) {                                       \
            bf16x8 b[4];                                                       \
            _Pragma("unroll")                                                  \
            for (int j = 0; j < 4; ++j)                                        \
                b[j] = *(const bf16x8*)(bp + (wn + jh * 64 + j * 16 + rr) * 32 + axo); \
            _Pragma("unroll")                                                  \
            for (int i = 0; i < 4; ++i)                                        \
                _Pragma("unroll")                                              \
                for (int j = 0; j < 4; ++j)                                    \
                    acc[i][jh * 4 + j] = __builtin_amdgcn_mfma_f32_16x16x32_bf16(a[i], b[j], acc[i][jh * 4 + j], 0, 0, 0); \
        }                                                                      \
        FN;                                                                    \
    }

    G1_STEP(0, FENCE(6));
    G1_STEP(1, FENCE(6));
    G1_STEP(2, FENCE(6));
    G1_STEP(3, FENCE(6));
    G1_STEP(4, FENCE(6));
    G1_STEP(5, FENCE(6));
    G1_STEP(6, FENCE(0));
    G1_STEP(7, ;);
#undef G1_STEP

    // epilogue: two 128-col passes through Cs (fully unrolled: static acc idx)
    const int cq  = (lane >> 4) * 4;
    const int cc  = lane & 15;
    const int lcb = wn >> 1;                 // local col base 0/64
#pragma unroll
    for (int p = 0; p < 2; ++p) {
        __syncthreads();                     // bufs done / prev writer done
        float bv[4];
#pragma unroll
        for (int j = 0; j < 4; ++j) bv[j] = b1[wn + p * 64 + j * 16 + cc];
#pragma unroll
        for (int i = 0; i < 4; ++i)
#pragma unroll
            for (int j = 0; j < 4; ++j) {
                const int col = lcb + j * 16 + cc;
#pragma unroll
                for (int rg = 0; rg < 4; ++rg)
                    Cs[(wm + i * 16 + cq + rg) * 136 + col] = f2bf(acc[i][p * 4 + j][rg] + bv[j]);
            }
        __syncthreads();
        {
            const int row = tid >> 1, hf = tid & 1;
            const unsigned short* src = Cs + row * 136 + hf * 64;
            unsigned short* dst = h1 + (m0 + row) * Cc + (hf * 2 + p) * 64;
#pragma unroll
            for (int i = 0; i < 8; ++i)
                *(uint4*)(dst + i * 8) = *(const uint4*)(src + i * 8);
        }
    }
}

// ---------------------------------------------------------------------------
// K2: depthwise 3x3 + bias + GELU + W-shift scatter, ONE BLOCK PER (b,h) ROW
// (grid 1024). Owns all writes to its gsh row: border zeros + barrier + the
// r5-proven quarter-row scatter loop. (r8/r10-proven, unchanged.)
// ---------------------------------------------------------------------------
__global__ __launch_bounds__(256)
void dwconv_gelu_scatter_kernel(const unsigned short* __restrict__ h1,
                                const float* __restrict__ dwT, const float* __restrict__ dw_b,
                                unsigned short* __restrict__ gsh)
{
    const int t   = threadIdx.x;
    const int bh  = blockIdx.x;       // b*128 + h
    const int bb  = bh >> 7, hh = bh & 127;
    const size_t rowb = (size_t)bb * Nc + (size_t)hh * Wc;

    // border zeros for this row: w in {0,1,126,127} x 256 ch (8B per thread)
    {
        const int wi = t >> 6;                       // 0..3
        const int w  = (wi & 2) ? (wi + 124) : wi;   // 0,1,126,127
        const int c8 = (t & 63) * 4;
        uint2 z; z.x = 0u; z.y = 0u;
        *(uint2*)(gsh + (rowb + w) * Cc + c8) = z;
    }
    __syncthreads();

    const int cg  = t & 31;           // channel group (8 ch): covers 256 ch
    const int wq  = t >> 5;           // w-quad 0..7
    const int c0  = cg * 8;
    const int s0  = c0 / CSZ - SPAD;
    const int s1  = (c0 + 4) / CSZ - SPAD;

#pragma unroll 1
    for (int qtr = 0; qtr < 4; ++qtr) {
        const int wbase = qtr * 32 + wq * 4 - 1;

        float acc[4][8];
        {
            float4 a0 = *(const float4*)(dw_b + c0);
            float4 a1 = *(const float4*)(dw_b + c0 + 4);
#pragma unroll
            for (int i = 0; i < 4; ++i) {
                acc[i][0] = a0.x; acc[i][1] = a0.y; acc[i][2] = a0.z; acc[i][3] = a0.w;
                acc[i][4] = a1.x; acc[i][5] = a1.y; acc[i][6] = a1.z; acc[i][7] = a1.w;
            }
        }

#pragma unroll
        for (int dy = -1; dy <= 1; ++dy) {
            const int y = hh + dy;
            if (y < 0 || y >= Hc) continue;          // block-uniform
            const unsigned short* rp = h1 + ((size_t)bb * Nc + (size_t)y * Wc) * Cc + c0;
            float in[6][8];
#pragma unroll
            for (int dx = 0; dx < 6; ++dx) {
                const int w = wbase + dx;
                ushort8 raw = {0, 0, 0, 0, 0, 0, 0, 0};
                if (w >= 0 && w < Wc) raw = *(const ushort8*)(rp + (size_t)w * Cc);
#pragma unroll
                for (int c = 0; c < 8; ++c) in[dx][c] = bf2f(raw[c]);
            }
            const float* wrow = dwT + (dy + 1) * 3 * Cc + c0;
            float wr[3][8];
#pragma unroll
            for (int tx = 0; tx < 3; ++tx) {
                float4 wa = *(const float4*)(wrow + tx * Cc);
                float4 wb = *(const float4*)(wrow + tx * Cc + 4);
                wr[tx][0] = wa.x; wr[tx][1] = wa.y; wr[tx][2] = wa.z; wr[tx][3] = wa.w;
                wr[tx][4] = wb.x; wr[tx][5] = wb.y; wr[tx][6] = wb.z; wr[tx][7] = wb.w;
            }
#pragma unroll
            for (int i = 0; i < 4; ++i)
#pragma unroll
                for (int tx = 0; tx < 3; ++tx)
#pragma unroll
                    for (int c = 0; c < 8; ++c)
                        acc[i][c] += in[i + tx][c] * wr[tx][c];
        }

#pragma unroll
        for (int i = 0; i < 4; ++i) {
            float g[8];
#pragma unroll
            for (int c = 0; c < 8; ++c) {
                const float v = acc[i][c];
                // gelu(v) ~= v * sigmoid(1.59576912*v + 0.07135482*v^3)
                const float u = v * v;
                const float a = __builtin_fmaf(0.0713548162f, u, 1.5957691216f);
                const float e = __expf(v * a);
                g[c] = v * e * __builtin_amdgcn_rcpf(e + 1.0f);
            }
            uint2 lo, hi;
            lo.x = pk2bf(g[0], g[1]); lo.y = pk2bf(g[2], g[3]);
            hi.x = pk2bf(g[4], g[5]); hi.y = pk2bf(g[6], g[7]);
            const int wo = wbase + 1 + i;
            const int w0 = wo + s0, w1 = wo + s1;
            if ((unsigned)w0 < (unsigned)Wc) *(uint2*)(gsh + (rowb + w0) * Cc + c0)     = lo;
            if ((unsigned)w1 < (unsigned)Wc) *(uint2*)(gsh + (rowb + w1) * Cc + c0 + 4) = hi;
        }
    }
}

// ---------------------------------------------------------------------------
// K3: out = g_shifted @ w2b^T + b2. Same 128x256 3-buffer counted-vmcnt
// pipeline as fc1; epilogue writes fp32 out directly (no Cs). LDS 73728,
// grid 1024.
// ---------------------------------------------------------------------------
__global__ __launch_bounds__(256)
void fc2_mfma_kernel(const unsigned short* __restrict__ A, const unsigned short* __restrict__ w2b,
                     const float* __restrict__ b2, float* __restrict__ out)
{
    __shared__ __align__(16) unsigned char sm[73728];

    const int tid  = threadIdx.x;
    const int lane = tid & 63;
    const int wave = tid >> 6;
    const int wm = (wave >> 1) * 64;
    const int wn = (wave & 1) * 128;

    const int lid = ((blockIdx.x & 7) << 7) | (blockIdx.x >> 3);
    const size_t m0 = (size_t)lid * 128;

    const int qa0 = tid, qa1 = tid + 256;
    const int ra0 = qa0 >> 2, ra1 = qa1 >> 2;
    const size_t aof0 = (m0 + ra0) * Cc + (((qa0 & 3) ^ (ra0 & 3)) << 3);
    const size_t aof1 = (m0 + ra1) * Cc + (((qa1 & 3) ^ (ra1 & 3)) << 3);
    const int qb0 = tid, qb1 = tid + 256, qb2 = tid + 512, qb3 = tid + 768;
    const int rb0 = qb0 >> 2, rb1 = qb1 >> 2, rb2 = qb2 >> 2, rb3 = qb3 >> 2;
    const int bof0 = rb0 * Cc + (((qb0 & 3) ^ (rb0 & 3)) << 3);
    const int bof1 = rb1 * Cc + (((qb1 & 3) ^ (rb1 & 3)) << 3);
    const int bof2 = rb2 * Cc + (((qb2 & 3) ^ (rb2 & 3)) << 3);
    const int bof3 = rb3 * Cc + (((qb3 & 3) ^ (rb3 & 3)) << 3);

    auto stage = [&](int buf, int t) {
        const int k0 = t * 32;
        unsigned char* ad = sm + buf * 24576;
        unsigned char* bd = ad + 8192;
        async16(A   + aof0 + k0, ad + qa0 * 16);
        async16(A   + aof1 + k0, ad + qa1 * 16);
        async16(w2b + bof0 + k0, bd + qb0 * 16);
        async16(w2b + bof1 + k0, bd + qb1 * 16);
        async16(w2b + bof2 + k0, bd + qb2 * 16);
        async16(w2b + bof3 + k0, bd + qb3 * 16);
    };

    f32x4 acc[4][8] = {};
    const int rr  = lane & 15;
    const int axo = (((lane >> 4) ^ (rr & 3)) << 3);

    stage(0, 0);
    stage(1, 1);
    FENCE(6);

#define G2_STEP(T, FN)                                                        \
    {                                                                          \
        if constexpr ((T) <= 5) stage(((T) + 2) % 3, (T) + 2);                 \
        const __bf16* ap = (const __bf16*)(sm + ((T) % 3) * 24576);            \
        const __bf16* bp = (const __bf16*)(sm + ((T) % 3) * 24576 + 8192);     \
        bf16x8 a[4];                                                           \
        _Pragma("unroll")                                                      \
        for (int i = 0; i < 4; ++i)                                            \
            a[i] = *(const bf16x8*)(ap + (wm + i * 16 + rr) * 32 + axo);       \
        _Pragma("unroll")                                                      \
        for (int jh = 0; jh < 2; ++jh) {                                       \
            bf16x8 b[4];                                                       \
            _Pragma("unroll")                                                  \
            for (int j = 0; j < 4; ++j)                                        \
                b[j] = *(const bf16x8*)(bp + (wn + jh * 64 + j * 16 + rr) * 32 + axo); \
            _Pragma("unroll")                                                  \
            for (int i = 0; i < 4; ++i)                                        \
                _Pragma("unroll")                                              \
                for (int j = 0; j < 4; ++j)                                    \
                    acc[i][jh * 4 + j] = __builtin_amdgcn_mfma_f32_16x16x32_bf16(a[i], b[j], acc[i][jh * 4 + j], 0, 0, 0); \
        }                                                                      \
        FN;                                                                    \
    }

    G2_STEP(0, FENCE(6));
    G2_STEP(1, FENCE(6));
    G2_STEP(2, FENCE(6));
    G2_STEP(3, FENCE(6));
    G2_STEP(4, FENCE(6));
    G2_STEP(5, FENCE(6));
    G2_STEP(6, FENCE(0));
    G2_STEP(7, ;);
#undef G2_STEP

    const int cq = (lane >> 4) * 4;
    const int cc = lane & 15;
    float bv[8];
#pragma unroll
    for (int jj = 0; jj < 8; ++jj)
        bv[jj] = b2[wn + (jj >> 2) * 64 + (jj & 3) * 16 + cc];
#pragma unroll
    for (int i = 0; i < 4; ++i)
#pragma unroll
        for (int jj = 0; jj < 8; ++jj) {
            const int col = wn + (jj >> 2) * 64 + (jj & 3) * 16 + cc;
#pragma unroll
            for (int rg = 0; rg < 4; ++rg)
                out[(m0 + wm + i * 16 + cq + rg) * Cc + col] = acc[i][jj][rg] + bv[jj];
        }
}

extern "C" void kernel_launch(void* const* d_in, const int* in_sizes, int n_in,
                              void* d_out, int out_size, void* d_ws, size_t ws_size,
                              hipStream_t stream) {
    // inputs: x, H, W, w1, b1, dw_w, dw_b, w2, b2
    const float* x    = (const float*)d_in[0];
    const float* w1   = (const float*)d_in[3];
    const float* b1   = (const float*)d_in[4];
    const float* dw_w = (const float*)d_in[5];
    const float* dw_b = (const float*)d_in[6];
    const float* w2   = (const float*)d_in[7];
    const float* b2   = (const float*)d_in[8];
    float* out = (float*)d_out;

    // ws layout:
    //   [0,64MB)    h1 bf16
    //   [64,128MB)  gsh bf16 (double-serves as xb: fc1 consumes it before
    //               dwconv overwrites; stream-serial)
    //   [128MB..)   w1b bf16 (128 KB), w2b bf16 (128 KB), dwT fp32 (9 KB)
    unsigned short* h1  = (unsigned short*)d_ws;
    unsigned short* gsh = h1 + (size_t)Mtot * Cc;
    unsigned short* w1b = gsh + (size_t)Mtot * Cc;
    unsigned short* w2b = w1b + 65536;
    float*          dwT = (float*)(w2b + 65536);

    shiftwprep_kernel<<<dim3(4096), dim3(256), 0, stream>>>(x, gsh, w1, w2, dw_w, w1b, w2b, dwT);
    fc1_mfma_kernel<<<dim3(Mtot / 128), dim3(256), 0, stream>>>(gsh, w1b, b1, h1);
    dwconv_gelu_scatter_kernel<<<dim3(Mtot / 128), dim3(256), 0, stream>>>(h1, dwT, dw_b, gsh);
    fc2_mfma_kernel<<<dim3(Mtot / 128), dim3(256), 0, stream>>>(gsh, w2b, b2, out);
}